// Round 12
// baseline (241.300 us; speedup 1.0000x reference)
//
#include <hip/hip_runtime.h>
#include <hip/hip_cooperative_groups.h>

namespace cg = cooperative_groups;

// MSMLTransformerLayer — single cooperative launch (R11 phase bodies + 3
// grid.sync), grid-stride jobs, all-short LDS overlay. Fallback: R11 4-launch.

#define DIM 256
#define NTOK 4096

typedef __attribute__((ext_vector_type(8))) short short8;
typedef __attribute__((ext_vector_type(4))) short short4v;
typedef __attribute__((ext_vector_type(4))) float f32x4;

struct UberParams {
    const float *x, *emb, *Wa, *ba, *lng, *lnb, *Wc, *bc, *Wq, *bq, *Wk, *bk,
                *pw, *pb, *Wl, *bl, *ng, *nb;
    short *h, *phik, *phiq, *kvT, *act, *Wkb, *Wqb, *Wlb;
    float* out;
};

__device__ __forceinline__ float silu_f(float z) { return z / (1.f + __expf(-z)); }
__device__ __forceinline__ float elu2_f(float z) { return z > 0.f ? z + 2.f : __expf(z) + 1.f; }

__device__ __forceinline__ short f2bf(float f) {
    union { float f; unsigned u; } v; v.f = f;
    unsigned r = v.u + 0x7fffu + ((v.u >> 16) & 1u);
    return (short)(r >> 16);
}
__device__ __forceinline__ float bf2f(short s) {
    union { unsigned u; float f; } v; v.u = ((unsigned)(unsigned short)s) << 16;
    return v.f;
}
__device__ __forceinline__ short8 cvt8(const float* src) {
    const float4 a = *(const float4*)src;
    const float4 c = *(const float4*)(src + 4);
    short8 s;
    s[0] = f2bf(a.x); s[1] = f2bf(a.y); s[2] = f2bf(a.z); s[3] = f2bf(a.w);
    s[4] = f2bf(c.x); s[5] = f2bf(c.y); s[6] = f2bf(c.z); s[7] = f2bf(c.w);
    return s;
}
__device__ __forceinline__ void cast_chunk(const float* __restrict__ src, short* __restrict__ dst,
                                           int chunk, int tid) {
    const int base = chunk * 8192 + tid * 32;
    #pragma unroll
    for (int j = 0; j < 4; ++j)
        *(short8*)(dst + base + j * 8) = cvt8(src + base + j * 8);
}

// ---------------- job: dual GEMM (silu); zz=0 act, zz=1 h (LN in-kernel) -----
__device__ __forceinline__ void job_dual(const UberParams& p, short* Xs, short* Ws, float* stats,
                                         int bx, int by, int zz, int tid) {
    const float* XF = p.x;
    const float* Wf = zz ? p.Wc : p.Wa;
    const float* bias = zz ? p.bc : p.ba;
    short* Y = zz ? p.h : p.act;
    const int wv = tid >> 6, l = tid & 63;
    const int lr = l & 15, lk = l >> 4;
    const int r0 = bx * 128, c0 = by * 64;
    const int wm = (wv >> 1) * 64, wn = (wv & 1) * 32;

    if (zz) {
        const int prow = tid >> 1, phalf = tid & 1;
        const float* src = XF + (size_t)(r0 + prow) * DIM + phalf * 128;
        float a1 = 0.f, a2 = 0.f;
        #pragma unroll 8
        for (int jj = 0; jj < 32; ++jj) {
            const float4 v = *(const float4*)(src + jj * 4);
            a1 += v.x + v.y + v.z + v.w;
            a2 += v.x * v.x + v.y * v.y + v.z * v.z + v.w * v.w;
        }
        a1 += __shfl_xor(a1, 1);
        a2 += __shfl_xor(a2, 1);
        if (!phalf) {
            const float mm = a1 * (1.f / DIM);
            stats[prow * 2] = mm;
            stats[prow * 2 + 1] = rsqrtf(a2 * (1.f / DIM) - mm * mm + 1e-5f);
        }
        __syncthreads();
    }

    f32x4 acc[4][2];
    #pragma unroll
    for (int i = 0; i < 4; ++i)
        #pragma unroll
        for (int j = 0; j < 2; ++j) acc[i][j] = (f32x4){0.f, 0.f, 0.f, 0.f};
    const int sr = tid >> 3, sc = (tid & 7) * 8;
    for (int kt = 0; kt < DIM; kt += 64) {
        float gv[8], bv[8];
        if (zz) {
            const float4 g1 = *(const float4*)(p.lng + kt + sc);
            const float4 g2 = *(const float4*)(p.lng + kt + sc + 4);
            const float4 t1 = *(const float4*)(p.lnb + kt + sc);
            const float4 t2 = *(const float4*)(p.lnb + kt + sc + 4);
            gv[0] = g1.x; gv[1] = g1.y; gv[2] = g1.z; gv[3] = g1.w;
            gv[4] = g2.x; gv[5] = g2.y; gv[6] = g2.z; gv[7] = g2.w;
            bv[0] = t1.x; bv[1] = t1.y; bv[2] = t1.z; bv[3] = t1.w;
            bv[4] = t2.x; bv[5] = t2.y; bv[6] = t2.z; bv[7] = t2.w;
        }
        #pragma unroll
        for (int pp = 0; pp < 4; ++pp) {
            const int row = sr + pp * 32;
            const float* src = XF + (size_t)(r0 + row) * DIM + kt + sc;
            const float4 a = *(const float4*)src;
            const float4 c = *(const float4*)(src + 4);
            float v[8] = {a.x, a.y, a.z, a.w, c.x, c.y, c.z, c.w};
            short8 s;
            if (zz) {
                const float mm = stats[row * 2], rs = stats[row * 2 + 1];
                #pragma unroll
                for (int j = 0; j < 8; ++j) s[j] = f2bf((v[j] - mm) * rs * gv[j] + bv[j]);
            } else {
                #pragma unroll
                for (int j = 0; j < 8; ++j) s[j] = f2bf(v[j]);
            }
            *(short8*)&Xs[row * 72 + sc] = s;
        }
        #pragma unroll
        for (int pp = 0; pp < 2; ++pp) {
            const int row = sr + pp * 32;
            *(short8*)&Ws[row * 72 + sc] = cvt8(Wf + (size_t)(c0 + row) * DIM + kt + sc);
        }
        __syncthreads();
        #pragma unroll
        for (int kc = 0; kc < 2; ++kc) {
            short8 af[4], bfr[2];
            #pragma unroll
            for (int mi = 0; mi < 4; ++mi)
                af[mi] = *(const short8*)&Xs[(wm + mi * 16 + lr) * 72 + kc * 32 + lk * 8];
            #pragma unroll
            for (int ni = 0; ni < 2; ++ni)
                bfr[ni] = *(const short8*)&Ws[(wn + ni * 16 + lr) * 72 + kc * 32 + lk * 8];
            #pragma unroll
            for (int mi = 0; mi < 4; ++mi)
                #pragma unroll
                for (int ni = 0; ni < 2; ++ni)
                    acc[mi][ni] = __builtin_amdgcn_mfma_f32_16x16x32_bf16(af[mi], bfr[ni], acc[mi][ni], 0, 0, 0);
        }
        __syncthreads();
    }
    #pragma unroll
    for (int mi = 0; mi < 4; ++mi)
        #pragma unroll
        for (int ni = 0; ni < 2; ++ni) {
            const int c = c0 + wn + ni * 16 + lr;
            const float bv2 = bias[c];
            #pragma unroll
            for (int i = 0; i < 4; ++i) {
                const int r = r0 + wm + mi * 16 + lk * 4 + i;
                Y[(size_t)r * DIM + c] = f2bf(silu_f(acc[mi][ni][i] + bv2));
            }
        }
}

// ---------------- job: k/q GEMM (elu+2); bx<64 phik, bx>=64 phiq -------------
__device__ __forceinline__ void job_kq(const UberParams& p, short* Xs, short* Ws,
                                       int bx, int by, int tid) {
    const bool isq = bx >= 64;
    const short* W = isq ? p.Wqb : p.Wkb;
    const float* bias = isq ? p.bq : p.bk;
    short* Y = isq ? p.phiq : p.phik;
    const int r0 = (isq ? bx - 64 : bx) * 128;
    const int c0 = by * 64;
    const int wv = tid >> 6, l = tid & 63;
    const int lr = l & 15, lk = l >> 4;
    const int wm = (wv >> 1) * 64, wn = (wv & 1) * 32;
    f32x4 acc[4][2];
    #pragma unroll
    for (int i = 0; i < 4; ++i)
        #pragma unroll
        for (int j = 0; j < 2; ++j) acc[i][j] = (f32x4){0.f, 0.f, 0.f, 0.f};
    const int sr = tid >> 3, sc = (tid & 7) * 8;
    for (int kt = 0; kt < DIM; kt += 64) {
        #pragma unroll
        for (int pp = 0; pp < 4; ++pp) {
            const int row = sr + pp * 32;
            int grow = r0 + row;
            if (isq) grow = ((grow >> 8) << 12) + (grow & 255);
            *(short8*)&Xs[row * 72 + sc] = *(const short8*)(p.h + (size_t)grow * DIM + kt + sc);
        }
        #pragma unroll
        for (int pp = 0; pp < 2; ++pp) {
            const int row = sr + pp * 32;
            *(short8*)&Ws[row * 72 + sc] = *(const short8*)(W + (size_t)(c0 + row) * DIM + kt + sc);
        }
        __syncthreads();
        #pragma unroll
        for (int kc = 0; kc < 2; ++kc) {
            short8 af[4], bfr[2];
            #pragma unroll
            for (int mi = 0; mi < 4; ++mi)
                af[mi] = *(const short8*)&Xs[(wm + mi * 16 + lr) * 72 + kc * 32 + lk * 8];
            #pragma unroll
            for (int ni = 0; ni < 2; ++ni)
                bfr[ni] = *(const short8*)&Ws[(wn + ni * 16 + lr) * 72 + kc * 32 + lk * 8];
            #pragma unroll
            for (int mi = 0; mi < 4; ++mi)
                #pragma unroll
                for (int ni = 0; ni < 2; ++ni)
                    acc[mi][ni] = __builtin_amdgcn_mfma_f32_16x16x32_bf16(af[mi], bfr[ni], acc[mi][ni], 0, 0, 0);
        }
        __syncthreads();
    }
    #pragma unroll
    for (int mi = 0; mi < 4; ++mi)
        #pragma unroll
        for (int ni = 0; ni < 2; ++ni) {
            const int c = c0 + wn + ni * 16 + lr;
            const float bv = bias[c];
            #pragma unroll
            for (int i = 0; i < 4; ++i) {
                const int r = r0 + wm + mi * 16 + lk * 4 + i;
                Y[(size_t)r * DIM + c] = f2bf(elu2_f(acc[mi][ni][i] + bv));
            }
        }
}

// ---------------- job: KV -----------------------------------------------------
__device__ __forceinline__ void job_kv(const UberParams& p, short* Hs, short* Ps,
                                       int bm, int d0, int c0, int tid) {
    const int b = bm >> 4, m = bm & 15;
    const int wv = tid >> 6, l = tid & 63;
    const int lr = l & 15, lk = l >> 4;
    const int wd = (wv >> 1) * 32, wc = (wv & 1) * 32;
    f32x4 acc[2][2];
    #pragma unroll
    for (int i = 0; i < 2; ++i)
        #pragma unroll
        for (int j = 0; j < 2; ++j) acc[i][j] = (f32x4){0.f, 0.f, 0.f, 0.f};
    const size_t hbase = (size_t)b * NTOK * DIM;
    const int sr = tid >> 3, sc = (tid & 7) * 8;
    for (int kt = 0; kt < 256; kt += 64) {
        #pragma unroll
        for (int pp = 0; pp < 2; ++pp) {
            const int w = sr + pp * 32;
            const size_t gg = hbase + (size_t)((kt + w) * 16 + m) * DIM;
            short8 hv = *(const short8*)(p.h + gg + d0 + sc);
            short8 pv = *(const short8*)(p.phik + gg + c0 + sc);
            *(short4v*)&Hs[w * 68 + sc]     = __builtin_shufflevector(hv, hv, 0, 1, 2, 3);
            *(short4v*)&Hs[w * 68 + sc + 4] = __builtin_shufflevector(hv, hv, 4, 5, 6, 7);
            *(short4v*)&Ps[w * 68 + sc]     = __builtin_shufflevector(pv, pv, 0, 1, 2, 3);
            *(short4v*)&Ps[w * 68 + sc + 4] = __builtin_shufflevector(pv, pv, 4, 5, 6, 7);
        }
        __syncthreads();
        #pragma unroll
        for (int kc = 0; kc < 2; ++kc) {
            const int kb = kc * 32 + lk * 8;
            short8 af[2], bfr[2];
            #pragma unroll
            for (int di = 0; di < 2; ++di)
                #pragma unroll
                for (int i = 0; i < 8; ++i)
                    af[di][i] = Hs[(kb + i) * 68 + wd + di * 16 + lr];
            #pragma unroll
            for (int ci = 0; ci < 2; ++ci)
                #pragma unroll
                for (int i = 0; i < 8; ++i)
                    bfr[ci][i] = Ps[(kb + i) * 68 + wc + ci * 16 + lr];
            #pragma unroll
            for (int di = 0; di < 2; ++di)
                #pragma unroll
                for (int ci = 0; ci < 2; ++ci)
                    acc[di][ci] = __builtin_amdgcn_mfma_f32_16x16x32_bf16(af[di], bfr[ci], acc[di][ci], 0, 0, 0);
        }
        __syncthreads();
    }
    #pragma unroll
    for (int di = 0; di < 2; ++di)
        #pragma unroll
        for (int ci = 0; ci < 2; ++ci)
            #pragma unroll
            for (int i = 0; i < 4; ++i) {
                const int d = d0 + wd + di * 16 + lk * 4 + i;
                const int c = c0 + wc + ci * 16 + lr;
                p.kvT[((size_t)bm * DIM + d) * DIM + c] = f2bf(acc[di][ci][i]);
            }
}

// ---------------- job: attlin -------------------------------------------------
__device__ __forceinline__ void job_attlin(const UberParams& p, short* Qs, short* AGs, short* Bs,
                                           float* s1buf, float* s2buf, int bm, int q0, int tid) {
    const int b = bm >> 4, m = bm & 15;
    const int wv = tid >> 6, l = tid & 63;
    const int lr = l & 15, lk = l >> 4;
    const int wq = (wv >> 1) * 16;
    const int wd = (wv & 1) * 32;
    const int sr = tid >> 3, sc = (tid & 7) * 8;

    #pragma unroll
    for (int pp = 0; pp < 4; ++pp) {
        const int chunk = tid + pp * 256;
        const int row = chunk >> 5, cc = (chunk & 31) * 8;
        *(short8*)&Qs[row * 264 + cc] = *(const short8*)(p.phiq + (size_t)(b * 256 + q0 + row) * DIM + cc);
    }

    f32x4 accA[4][2];
    #pragma unroll
    for (int i = 0; i < 4; ++i)
        #pragma unroll
        for (int j = 0; j < 2; ++j) accA[i][j] = (f32x4){0.f, 0.f, 0.f, 0.f};
    for (int kt = 0; kt < DIM; kt += 64) {
        #pragma unroll
        for (int pp = 0; pp < 8; ++pp) {
            const int row = sr + pp * 32;
            *(short8*)&Bs[row * 72 + sc] = *(const short8*)(p.kvT + ((size_t)bm * DIM + row) * DIM + kt + sc);
        }
        __syncthreads();
        #pragma unroll
        for (int kc = 0; kc < 2; ++kc) {
            const short8 af = *(const short8*)&Qs[(wq + lr) * 264 + kt + kc * 32 + lk * 8];
            #pragma unroll
            for (int dc = 0; dc < 4; ++dc)
                #pragma unroll
                for (int ni = 0; ni < 2; ++ni) {
                    const short8 bfr = *(const short8*)&Bs[(dc * 64 + wd + ni * 16 + lr) * 72 + kc * 32 + lk * 8];
                    accA[dc][ni] = __builtin_amdgcn_mfma_f32_16x16x32_bf16(af, bfr, accA[dc][ni], 0, 0, 0);
                }
        }
        __syncthreads();
    }
    {
        const float pw0 = p.pw[0], pw1 = p.pw[1], pw2 = p.pw[2], pbv = p.pb[0];
        #pragma unroll
        for (int i = 0; i < 4; ++i) {
            const int rloc = wq + lk * 4 + i;
            const int qr = q0 + rloc;
            const int widx = qr >> 4, nidx = qr & 15;
            const float* e = p.emb + ((((size_t)(2 + b) * 256 + widx) * 16 + nidx) * 16 + m) * 3;
            const float pv = e[0] * pw0 + e[1] * pw1 + e[2] * pw2 + pbv;
            const int t = qr * 16 + m;
            #pragma unroll
            for (int dc = 0; dc < 4; ++dc)
                #pragma unroll
                for (int ni = 0; ni < 2; ++ni) {
                    const int d = dc * 64 + wd + ni * 16 + lr;
                    const size_t o = ((size_t)b * NTOK + t) * DIM + d;
                    AGs[rloc * 264 + d] = f2bf((accA[dc][ni][i] + pv) * bf2f(p.act[o]));
                }
        }
    }
    __syncthreads();

    const int wn2 = (wv & 1) * 128;
    f32x4 accB[8];
    #pragma unroll
    for (int i = 0; i < 8; ++i) accB[i] = (f32x4){0.f, 0.f, 0.f, 0.f};
    for (int kt = 0; kt < DIM; kt += 64) {
        #pragma unroll
        for (int pp = 0; pp < 8; ++pp) {
            const int row = sr + pp * 32;
            *(short8*)&Bs[row * 72 + sc] = *(const short8*)(p.Wlb + (size_t)row * DIM + kt + sc);
        }
        __syncthreads();
        #pragma unroll
        for (int kc = 0; kc < 2; ++kc) {
            const short8 af = *(const short8*)&AGs[(wq + lr) * 264 + kt + kc * 32 + lk * 8];
            #pragma unroll
            for (int ni = 0; ni < 8; ++ni) {
                const short8 bfr = *(const short8*)&Bs[(wn2 + ni * 16 + lr) * 72 + kc * 32 + lk * 8];
                accB[ni] = __builtin_amdgcn_mfma_f32_16x16x32_bf16(af, bfr, accB[ni], 0, 0, 0);
            }
        }
        __syncthreads();
    }
    float s1[4] = {0.f, 0.f, 0.f, 0.f}, s2[4] = {0.f, 0.f, 0.f, 0.f};
    #pragma unroll
    for (int ni = 0; ni < 8; ++ni) {
        const int col = wn2 + ni * 16 + lr;
        const float bv = p.bl[col];
        #pragma unroll
        for (int i = 0; i < 4; ++i) {
            const int rloc = wq + lk * 4 + i;
            const int t = (q0 + rloc) * 16 + m;
            const float z = accB[ni][i] + bv + bf2f(p.h[((size_t)b * NTOK + t) * DIM + col]);
            accB[ni][i] = z;
            s1[i] += z; s2[i] += z * z;
        }
    }
    #pragma unroll
    for (int o = 1; o < 16; o <<= 1) {
        #pragma unroll
        for (int i = 0; i < 4; ++i) {
            s1[i] += __shfl_xor(s1[i], o);
            s2[i] += __shfl_xor(s2[i], o);
        }
    }
    if (lr == 0) {
        #pragma unroll
        for (int i = 0; i < 4; ++i) {
            const int rloc = wq + lk * 4 + i;
            s1buf[rloc * 2 + (wv & 1)] = s1[i];
            s2buf[rloc * 2 + (wv & 1)] = s2[i];
        }
    }
    __syncthreads();
    float mean[4], rstd[4];
    #pragma unroll
    for (int i = 0; i < 4; ++i) {
        const int rloc = wq + lk * 4 + i;
        const float t1 = s1buf[rloc * 2] + s1buf[rloc * 2 + 1];
        const float t2 = s2buf[rloc * 2] + s2buf[rloc * 2 + 1];
        const float mm = t1 * (1.f / DIM);
        mean[i] = mm;
        rstd[i] = rsqrtf(t2 * (1.f / DIM) - mm * mm + 1e-5f);
    }
    #pragma unroll
    for (int ni = 0; ni < 8; ++ni) {
        const int col = wn2 + ni * 16 + lr;
        const float gv = p.ng[col], bv2 = p.nb[col];
        #pragma unroll
        for (int i = 0; i < 4; ++i) {
            const int rloc = wq + lk * 4 + i;
            const int t = (q0 + rloc) * 16 + m;
            p.out[((size_t)b * NTOK + t) * DIM + col] = (accB[ni][i] - mean[i]) * rstd[i] * gv + bv2;
        }
    }
}

// ================= cooperative uber kernel ===================================
__global__ __launch_bounds__(256) void uber(UberParams p) {
    __shared__ __align__(16) short SBUF[35328];
    __shared__ float FBUF[256];
    cg::grid_group g = cg::this_grid();
    const int bid = blockIdx.x, G = gridDim.x, tid = threadIdx.x;

    // phase A: weight casts + dual GEMM (512 jobs)
    for (int j = bid; j < 24; j += G) {
        if (j < 8) cast_chunk(p.Wk, p.Wkb, j, tid);
        else if (j < 16) cast_chunk(p.Wq, p.Wqb, j - 8, tid);
        else cast_chunk(p.Wl, p.Wlb, j - 16, tid);
    }
    for (int j = bid; j < 512; j += G)
        job_dual(p, SBUF, SBUF + 9216, FBUF, j & 63, (j >> 6) & 3, j >> 8, tid);
    __threadfence();
    g.sync();

    // phase B: kq (272 jobs)
    for (int j = bid; j < 272; j += G)
        job_kq(p, SBUF, SBUF + 9216, j % 68, j / 68, tid);
    __threadfence();
    g.sync();

    // phase C: kv (512 jobs)
    for (int j = bid; j < 512; j += G)
        job_kv(p, SBUF, SBUF + 4352, j % 32, ((j >> 5) & 3) * 64, (j >> 7) * 64, tid);
    __threadfence();
    g.sync();

    // phase D: attlin (256 jobs)
    for (int j = bid; j < 256; j += G)
        job_attlin(p, SBUF, SBUF + 8448, SBUF + 16896, FBUF, FBUF + 64, j % 32, (j >> 5) * 32, tid);
}

// ================= fallback standalone kernels (R11 path) ====================
__global__ __launch_bounds__(256) void k_dual(UberParams p) {
    __shared__ __align__(16) short Xs[128 * 72];
    __shared__ __align__(16) short Ws[64 * 72];
    __shared__ float stats[256];
    if (blockIdx.x >= 64) {
        if (blockIdx.y == 0 && blockIdx.z == 0) {
            const int which = blockIdx.x - 64;
            if (which < 8) cast_chunk(p.Wk, p.Wkb, which, threadIdx.x);
            else if (which < 16) cast_chunk(p.Wq, p.Wqb, which - 8, threadIdx.x);
            else cast_chunk(p.Wl, p.Wlb, which - 16, threadIdx.x);
        }
        return;
    }
    job_dual(p, Xs, Ws, stats, blockIdx.x, blockIdx.y, blockIdx.z, threadIdx.x);
}
__global__ __launch_bounds__(256) void k_kq(UberParams p) {
    __shared__ __align__(16) short Xs[128 * 72];
    __shared__ __align__(16) short Ws[64 * 72];
    job_kq(p, Xs, Ws, blockIdx.x, blockIdx.y, threadIdx.x);
}
__global__ __launch_bounds__(256) void k_kv(UberParams p) {
    __shared__ __align__(16) short Hs[64 * 68];
    __shared__ __align__(16) short Ps[64 * 68];
    job_kv(p, Hs, Ps, blockIdx.x, blockIdx.y * 64, blockIdx.z * 64, threadIdx.x);
}
__global__ __launch_bounds__(256) void k_attlin(UberParams p) {
    __shared__ __align__(16) short Qs[32 * 264];
    __shared__ __align__(16) short AGs[32 * 264];
    __shared__ __align__(16) short Bs[256 * 72];
    __shared__ float s1buf[64];
    __shared__ float s2buf[64];
    job_attlin(p, Qs, AGs, Bs, s1buf, s2buf, blockIdx.x, blockIdx.y * 32, threadIdx.x);
}

extern "C" void kernel_launch(void* const* d_in, const int* in_sizes, int n_in,
                              void* d_out, int out_size, void* d_ws, size_t ws_size,
                              hipStream_t stream) {
    char* ws = (char*)d_ws;
    const size_t MB = 1024 * 1024;

    UberParams p;
    p.x   = (const float*)d_in[0];
    p.emb = (const float*)d_in[1];
    p.Wa  = (const float*)d_in[2];
    p.ba  = (const float*)d_in[3];
    p.lng = (const float*)d_in[4];
    p.lnb = (const float*)d_in[5];
    p.Wc  = (const float*)d_in[6];
    p.bc  = (const float*)d_in[7];
    p.Wq  = (const float*)d_in[8];
    p.bq  = (const float*)d_in[9];
    p.Wk  = (const float*)d_in[10];
    p.bk  = (const float*)d_in[11];
    p.pw  = (const float*)d_in[12];
    p.pb  = (const float*)d_in[13];
    p.Wl  = (const float*)d_in[14];
    p.bl  = (const float*)d_in[15];
    p.ng  = (const float*)d_in[16];
    p.nb  = (const float*)d_in[17];
    p.h    = (short*)(ws + 0 * MB);
    p.phik = (short*)(ws + 4 * MB);
    p.phiq = (short*)(ws + 8 * MB);
    p.kvT  = (short*)(ws + 9 * MB);
    p.act  = (short*)(ws + 13 * MB);
    p.Wkb  = (short*)(ws + 17 * MB);
    p.Wqb  = (short*)(ws + 17 * MB + 128 * 1024);
    p.Wlb  = (short*)(ws + 17 * MB + 256 * 1024);
    p.out  = (float*)d_out;

    int nb = 0;
    hipError_t oe = hipOccupancyMaxActiveBlocksPerMultiprocessor(&nb, (const void*)uber, 256, 0);
    int grid = (oe == hipSuccess && nb > 0) ? nb * 256 : 0;
    if (grid > 512) grid = 512;
    if (grid >= 64) {
        void* args[] = { &p };
        if (hipLaunchCooperativeKernel((const void*)uber, dim3(grid), dim3(256),
                                       args, 0, stream) == hipSuccess)
            return;
    }
    // fallback: proven 4-launch path
    k_dual<<<dim3(88, 4, 2), dim3(256), 0, stream>>>(p);
    k_kq<<<dim3(68, 4), dim3(256), 0, stream>>>(p);
    k_kv<<<dim3(32, 4, 4), dim3(256), 0, stream>>>(p);
    k_attlin<<<dim3(32, 8), dim3(256), 0, stream>>>(p);
}

// Round 13
// 58.710 us; speedup vs baseline: 4.1100x; 4.1100x over previous
//
#include <hip/hip_runtime.h>

// MSMLTransformerLayer — 3 launches (R12 coop g.sync = 398µs, abandoned).
// S1 dual(act,h + Wk/Wq/Wl casts) -> S2 kv_fused(inline phik recompute) ->
// S3 attlin_fused(inline phiq recompute + att + lin + residual + final LN).
// phik/phiq no longer materialized.

#define DIM 256
#define NTOK 4096

typedef __attribute__((ext_vector_type(8))) short short8;
typedef __attribute__((ext_vector_type(4))) short short4v;
typedef __attribute__((ext_vector_type(4))) float f32x4;

__device__ __forceinline__ float silu_f(float z) { return z / (1.f + __expf(-z)); }
__device__ __forceinline__ float elu2_f(float z) { return z > 0.f ? z + 2.f : __expf(z) + 1.f; }

__device__ __forceinline__ short f2bf(float f) {
    union { float f; unsigned u; } v; v.f = f;
    unsigned r = v.u + 0x7fffu + ((v.u >> 16) & 1u);
    return (short)(r >> 16);
}
__device__ __forceinline__ float bf2f(short s) {
    union { unsigned u; float f; } v; v.u = ((unsigned)(unsigned short)s) << 16;
    return v.f;
}
__device__ __forceinline__ short8 cvt8(const float* src) {
    const float4 a = *(const float4*)src;
    const float4 c = *(const float4*)(src + 4);
    short8 s;
    s[0] = f2bf(a.x); s[1] = f2bf(a.y); s[2] = f2bf(a.z); s[3] = f2bf(a.w);
    s[4] = f2bf(c.x); s[5] = f2bf(c.y); s[6] = f2bf(c.z); s[7] = f2bf(c.w);
    return s;
}
__device__ __forceinline__ void cast_chunk(const float* __restrict__ src, short* __restrict__ dst,
                                           int chunk, int tid) {
    const int base = chunk * 8192 + tid * 32;
    #pragma unroll
    for (int j = 0; j < 4; ++j)
        *(short8*)(dst + base + j * 8) = cvt8(src + base + j * 8);
}

// ---------------- S1: fused dual GEMM (silu) + Wk/Wq/Wl cast side-blocks -----
// grid (88,4,2): x<64 GEMM tile 128x64; x in [64,88) casts (y==0,z==0).
__global__ __launch_bounds__(256) void fused_dual(
        const float* __restrict__ XF,
        const float* __restrict__ W0f, const float* __restrict__ b0, short* __restrict__ Y0,
        const float* __restrict__ W1f, const float* __restrict__ b1, short* __restrict__ Y1,
        const float* __restrict__ G, const float* __restrict__ Bt,
        const float* __restrict__ Wkf, short* __restrict__ WKB,
        const float* __restrict__ Wqf, short* __restrict__ WQB,
        const float* __restrict__ Wlf, short* __restrict__ WLB) {
    const int tid = threadIdx.x;
    if (blockIdx.x >= 64) {
        if (blockIdx.y == 0 && blockIdx.z == 0) {
            const int which = blockIdx.x - 64;
            if (which < 8) cast_chunk(Wkf, WKB, which, tid);
            else if (which < 16) cast_chunk(Wqf, WQB, which - 8, tid);
            else cast_chunk(Wlf, WLB, which - 16, tid);
        }
        return;
    }
    __shared__ __align__(16) short Xs[128 * 72];
    __shared__ __align__(16) short Ws[64 * 72];
    __shared__ float stats[128][2];
    const int zz = blockIdx.z;
    const float* Wf = zz ? W1f : W0f;
    const float* bias = zz ? b1 : b0;
    short* Y = zz ? Y1 : Y0;
    const int wv = tid >> 6, l = tid & 63;
    const int lr = l & 15, lk = l >> 4;
    const int r0 = blockIdx.x * 128, c0 = blockIdx.y * 64;
    const int wm = (wv >> 1) * 64, wn = (wv & 1) * 32;

    if (zz) {
        const int prow = tid >> 1, phalf = tid & 1;
        const float* src = XF + (size_t)(r0 + prow) * DIM + phalf * 128;
        float a1 = 0.f, a2 = 0.f;
        #pragma unroll 8
        for (int jj = 0; jj < 32; ++jj) {
            const float4 v = *(const float4*)(src + jj * 4);
            a1 += v.x + v.y + v.z + v.w;
            a2 += v.x * v.x + v.y * v.y + v.z * v.z + v.w * v.w;
        }
        a1 += __shfl_xor(a1, 1);
        a2 += __shfl_xor(a2, 1);
        if (!phalf) {
            const float mm = a1 * (1.f / DIM);
            stats[prow][0] = mm;
            stats[prow][1] = rsqrtf(a2 * (1.f / DIM) - mm * mm + 1e-5f);
        }
        __syncthreads();
    }

    f32x4 acc[4][2];
    #pragma unroll
    for (int i = 0; i < 4; ++i)
        #pragma unroll
        for (int j = 0; j < 2; ++j) acc[i][j] = (f32x4){0.f, 0.f, 0.f, 0.f};
    const int sr = tid >> 3, sc = (tid & 7) * 8;
    for (int kt = 0; kt < DIM; kt += 64) {
        float gv[8], bv[8];
        if (zz) {
            const float4 g1 = *(const float4*)(G + kt + sc);
            const float4 g2 = *(const float4*)(G + kt + sc + 4);
            const float4 t1 = *(const float4*)(Bt + kt + sc);
            const float4 t2 = *(const float4*)(Bt + kt + sc + 4);
            gv[0] = g1.x; gv[1] = g1.y; gv[2] = g1.z; gv[3] = g1.w;
            gv[4] = g2.x; gv[5] = g2.y; gv[6] = g2.z; gv[7] = g2.w;
            bv[0] = t1.x; bv[1] = t1.y; bv[2] = t1.z; bv[3] = t1.w;
            bv[4] = t2.x; bv[5] = t2.y; bv[6] = t2.z; bv[7] = t2.w;
        }
        #pragma unroll
        for (int pp = 0; pp < 4; ++pp) {
            const int row = sr + pp * 32;
            const float* src = XF + (size_t)(r0 + row) * DIM + kt + sc;
            const float4 a = *(const float4*)src;
            const float4 c = *(const float4*)(src + 4);
            float v[8] = {a.x, a.y, a.z, a.w, c.x, c.y, c.z, c.w};
            short8 s;
            if (zz) {
                const float mm = stats[row][0], rs = stats[row][1];
                #pragma unroll
                for (int j = 0; j < 8; ++j) s[j] = f2bf((v[j] - mm) * rs * gv[j] + bv[j]);
            } else {
                #pragma unroll
                for (int j = 0; j < 8; ++j) s[j] = f2bf(v[j]);
            }
            *(short8*)&Xs[row * 72 + sc] = s;
        }
        #pragma unroll
        for (int pp = 0; pp < 2; ++pp) {
            const int row = sr + pp * 32;
            *(short8*)&Ws[row * 72 + sc] = cvt8(Wf + (size_t)(c0 + row) * DIM + kt + sc);
        }
        __syncthreads();
        #pragma unroll
        for (int kc = 0; kc < 2; ++kc) {
            short8 af[4], bfr[2];
            #pragma unroll
            for (int mi = 0; mi < 4; ++mi)
                af[mi] = *(const short8*)&Xs[(wm + mi * 16 + lr) * 72 + kc * 32 + lk * 8];
            #pragma unroll
            for (int ni = 0; ni < 2; ++ni)
                bfr[ni] = *(const short8*)&Ws[(wn + ni * 16 + lr) * 72 + kc * 32 + lk * 8];
            #pragma unroll
            for (int mi = 0; mi < 4; ++mi)
                #pragma unroll
                for (int ni = 0; ni < 2; ++ni)
                    acc[mi][ni] = __builtin_amdgcn_mfma_f32_16x16x32_bf16(af[mi], bfr[ni], acc[mi][ni], 0, 0, 0);
        }
        __syncthreads();
    }
    #pragma unroll
    for (int mi = 0; mi < 4; ++mi)
        #pragma unroll
        for (int ni = 0; ni < 2; ++ni) {
            const int c = c0 + wn + ni * 16 + lr;
            const float bv2 = bias[c];
            #pragma unroll
            for (int i = 0; i < 4; ++i) {
                const int r = r0 + wm + mi * 16 + lk * 4 + i;
                Y[(size_t)r * DIM + c] = f2bf(silu_f(acc[mi][ni][i] + bv2));
            }
        }
}

// ---------------- S2: kv_fused — inline phik recompute -----------------------
// grid (32,4,2): (bm, c-panel/64, d-half/128). Per 64-window chunk:
// stage h rows (full K) -> P = elu2(h @ Wk-panel^T + bk) -> KV += h^T @ P.
__global__ __launch_bounds__(256) void kv_fused(
        const short* __restrict__ HB, const short* __restrict__ WKB,
        const float* __restrict__ bk, short* __restrict__ KVT) {
    __shared__ __align__(16) short Wres[64 * 264];
    __shared__ __align__(16) short Hs[64 * 264];
    __shared__ __align__(16) short Ps[64 * 68];
    const int tid = threadIdx.x;
    const int bm = blockIdx.x, b = bm >> 4, m = bm & 15;
    const int c0 = blockIdx.y * 64;
    const int dh = blockIdx.z * 128;
    const int wv = tid >> 6, l = tid & 63;
    const int lr = l & 15, lk = l >> 4;
    const int wd2 = (wv >> 1) * 64, wc2 = (wv & 1) * 32;  // KV wave tile 64d x 32c
    const int pw_ = (wv >> 1) * 32, pc_ = (wv & 1) * 32;  // P  wave tile 32w x 32c

    // stage Wk c-panel, full K (bf16 source)
    #pragma unroll
    for (int pp = 0; pp < 8; ++pp) {
        const int chunk = tid + pp * 256;
        const int row = chunk >> 5, cc = (chunk & 31) * 8;
        *(short8*)&Wres[row * 264 + cc] = *(const short8*)(WKB + (size_t)(c0 + row) * DIM + cc);
    }

    f32x4 acc[4][2];
    #pragma unroll
    for (int i = 0; i < 4; ++i)
        #pragma unroll
        for (int j = 0; j < 2; ++j) acc[i][j] = (f32x4){0.f, 0.f, 0.f, 0.f};
    const size_t hbase = (size_t)b * NTOK * DIM;
    __syncthreads();

    for (int ch = 0; ch < 4; ++ch) {
        // stage 64 h rows (windows ch*64+w, token = w*16+m), full K=256
        #pragma unroll
        for (int pp = 0; pp < 8; ++pp) {
            const int chunk = tid + pp * 256;
            const int row = chunk >> 5, cc = (chunk & 31) * 8;
            const size_t g = hbase + (size_t)(((ch * 64 + row) * 16) + m) * DIM + cc;
            *(short8*)&Hs[row * 264 + cc] = *(const short8*)(HB + g);
        }
        __syncthreads();
        // P = elu2(Hs @ Wres^T + bk): 64w x 64c, K=256
        f32x4 pacc[2][2];
        #pragma unroll
        for (int i = 0; i < 2; ++i)
            #pragma unroll
            for (int j = 0; j < 2; ++j) pacc[i][j] = (f32x4){0.f, 0.f, 0.f, 0.f};
        for (int kt = 0; kt < DIM; kt += 64) {
            #pragma unroll
            for (int kc = 0; kc < 2; ++kc) {
                short8 af[2], bfr[2];
                #pragma unroll
                for (int mi = 0; mi < 2; ++mi)
                    af[mi] = *(const short8*)&Hs[(pw_ + mi * 16 + lr) * 264 + kt + kc * 32 + lk * 8];
                #pragma unroll
                for (int ni = 0; ni < 2; ++ni)
                    bfr[ni] = *(const short8*)&Wres[(pc_ + ni * 16 + lr) * 264 + kt + kc * 32 + lk * 8];
                #pragma unroll
                for (int mi = 0; mi < 2; ++mi)
                    #pragma unroll
                    for (int ni = 0; ni < 2; ++ni)
                        pacc[mi][ni] = __builtin_amdgcn_mfma_f32_16x16x32_bf16(af[mi], bfr[ni], pacc[mi][ni], 0, 0, 0);
            }
        }
        #pragma unroll
        for (int mi = 0; mi < 2; ++mi)
            #pragma unroll
            for (int ni = 0; ni < 2; ++ni) {
                const int cloc = pc_ + ni * 16 + lr;
                const float bv = bk[c0 + cloc];
                #pragma unroll
                for (int i = 0; i < 4; ++i)
                    Ps[(pw_ + mi * 16 + lk * 4 + i) * 68 + cloc] = f2bf(elu2_f(pacc[mi][ni][i] + bv));
            }
        __syncthreads();
        // KV += h^T @ P over this chunk's 64 rows (K=64)
        #pragma unroll
        for (int kc = 0; kc < 2; ++kc) {
            const int kb = kc * 32 + lk * 8;
            short8 af2[4], bfr2[2];
            #pragma unroll
            for (int di = 0; di < 4; ++di)
                #pragma unroll
                for (int i = 0; i < 8; ++i)
                    af2[di][i] = Hs[(kb + i) * 264 + dh + wd2 + di * 16 + lr];
            #pragma unroll
            for (int ci = 0; ci < 2; ++ci)
                #pragma unroll
                for (int i = 0; i < 8; ++i)
                    bfr2[ci][i] = Ps[(kb + i) * 68 + wc2 + ci * 16 + lr];
            #pragma unroll
            for (int di = 0; di < 4; ++di)
                #pragma unroll
                for (int ci = 0; ci < 2; ++ci)
                    acc[di][ci] = __builtin_amdgcn_mfma_f32_16x16x32_bf16(af2[di], bfr2[ci], acc[di][ci], 0, 0, 0);
        }
        __syncthreads();
    }
    #pragma unroll
    for (int di = 0; di < 4; ++di)
        #pragma unroll
        for (int ci = 0; ci < 2; ++ci)
            #pragma unroll
            for (int i = 0; i < 4; ++i) {
                const int d = dh + wd2 + di * 16 + lk * 4 + i;
                const int c = c0 + wc2 + ci * 16 + lr;
                KVT[((size_t)bm * DIM + d) * DIM + c] = f2bf(acc[di][ci][i]);
            }
}

// ---------------- S3: attlin_fused — inline phiq + att + lin + LN ------------
// grid (32,8): (bm, q-chunk of 32 tokens). Phase 0: phiq -> Qs;
// phase A: AG = (Qs @ kvT^T + p)*act; phase B: lin + residual + final LN.
__global__ __launch_bounds__(256) void attlin_fused(
        const short* __restrict__ HB, const short* __restrict__ WQB, const float* __restrict__ bq,
        const short* __restrict__ KVT,
        const float* __restrict__ emb, const float* __restrict__ pw, const float* __restrict__ pb,
        const short* __restrict__ AR,
        const short* __restrict__ WLB, const float* __restrict__ bl,
        const float* __restrict__ G, const float* __restrict__ Bt,
        float* __restrict__ Y) {
    __shared__ __align__(16) short Qs[32 * 264];
    __shared__ __align__(16) short AGs[32 * 264];
    __shared__ __align__(16) short Bs[256 * 72];
    __shared__ __align__(16) short h32s[32 * 72];
    __shared__ float s1buf[32][2];
    __shared__ float s2buf[32][2];
    const int tid = threadIdx.x;
    const int wv = tid >> 6, l = tid & 63;
    const int lr = l & 15, lk = l >> 4;
    const int bm = blockIdx.x, b = bm >> 4, m = bm & 15;
    const int q0 = blockIdx.y * 32;
    const int wq = (wv >> 1) * 16;
    const int wd = (wv & 1) * 32;
    const int wn2 = (wv & 1) * 128;
    const int sr = tid >> 3, sc = (tid & 7) * 8;

    // ---- phase 0: phiq = elu2(h[q-tokens] @ Wq^T + bq) -> Qs ----
    f32x4 acc0[8];
    #pragma unroll
    for (int i = 0; i < 8; ++i) acc0[i] = (f32x4){0.f, 0.f, 0.f, 0.f};
    for (int kt = 0; kt < DIM; kt += 64) {
        if (sr < 32)
            *(short8*)&h32s[sr * 72 + sc] = *(const short8*)(HB + (size_t)(b * NTOK + q0 + sr) * DIM + kt + sc);
        #pragma unroll
        for (int pp = 0; pp < 8; ++pp) {
            const int row = sr + pp * 32;
            *(short8*)&Bs[row * 72 + sc] = *(const short8*)(WQB + (size_t)row * DIM + kt + sc);
        }
        __syncthreads();
        #pragma unroll
        for (int kc = 0; kc < 2; ++kc) {
            const short8 af = *(const short8*)&h32s[(wq + lr) * 72 + kc * 32 + lk * 8];
            #pragma unroll
            for (int ni = 0; ni < 8; ++ni) {
                const short8 bfr = *(const short8*)&Bs[(wn2 + ni * 16 + lr) * 72 + kc * 32 + lk * 8];
                acc0[ni] = __builtin_amdgcn_mfma_f32_16x16x32_bf16(af, bfr, acc0[ni], 0, 0, 0);
            }
        }
        __syncthreads();
    }
    #pragma unroll
    for (int ni = 0; ni < 8; ++ni) {
        const int col = wn2 + ni * 16 + lr;
        const float bv = bq[col];
        #pragma unroll
        for (int i = 0; i < 4; ++i) {
            const int rloc = wq + lk * 4 + i;
            Qs[rloc * 264 + col] = f2bf(elu2_f(acc0[ni][i] + bv));
        }
    }
    __syncthreads();

    // ---- phase A: AG = (Qs @ kvT^T + p) * act_res -> AGs ----
    f32x4 accA[4][2];
    #pragma unroll
    for (int i = 0; i < 4; ++i)
        #pragma unroll
        for (int j = 0; j < 2; ++j) accA[i][j] = (f32x4){0.f, 0.f, 0.f, 0.f};
    for (int kt = 0; kt < DIM; kt += 64) {
        #pragma unroll
        for (int pp = 0; pp < 8; ++pp) {
            const int row = sr + pp * 32;
            *(short8*)&Bs[row * 72 + sc] = *(const short8*)(KVT + ((size_t)bm * DIM + row) * DIM + kt + sc);
        }
        __syncthreads();
        #pragma unroll
        for (int kc = 0; kc < 2; ++kc) {
            const short8 af = *(const short8*)&Qs[(wq + lr) * 264 + kt + kc * 32 + lk * 8];
            #pragma unroll
            for (int dc = 0; dc < 4; ++dc)
                #pragma unroll
                for (int ni = 0; ni < 2; ++ni) {
                    const short8 bfr = *(const short8*)&Bs[(dc * 64 + wd + ni * 16 + lr) * 72 + kc * 32 + lk * 8];
                    accA[dc][ni] = __builtin_amdgcn_mfma_f32_16x16x32_bf16(af, bfr, accA[dc][ni], 0, 0, 0);
                }
        }
        __syncthreads();
    }
    {
        const float pw0 = pw[0], pw1 = pw[1], pw2 = pw[2], pbv = pb[0];
        #pragma unroll
        for (int i = 0; i < 4; ++i) {
            const int rloc = wq + lk * 4 + i;
            const int qr = q0 + rloc;
            const int widx = qr >> 4, nidx = qr & 15;
            const float* e = emb + ((((size_t)(2 + b) * 256 + widx) * 16 + nidx) * 16 + m) * 3;
            const float pv = e[0] * pw0 + e[1] * pw1 + e[2] * pw2 + pbv;
            const int t = qr * 16 + m;
            #pragma unroll
            for (int dc = 0; dc < 4; ++dc)
                #pragma unroll
                for (int ni = 0; ni < 2; ++ni) {
                    const int d = dc * 64 + wd + ni * 16 + lr;
                    const size_t o = ((size_t)b * NTOK + t) * DIM + d;
                    AGs[rloc * 264 + d] = f2bf((accA[dc][ni][i] + pv) * bf2f(AR[o]));
                }
        }
    }
    __syncthreads();

    // ---- phase B: hid = AG @ Wl^T + bl + residual; final LN ----
    f32x4 accB[8];
    #pragma unroll
    for (int i = 0; i < 8; ++i) accB[i] = (f32x4){0.f, 0.f, 0.f, 0.f};
    for (int kt = 0; kt < DIM; kt += 64) {
        #pragma unroll
        for (int pp = 0; pp < 8; ++pp) {
            const int row = sr + pp * 32;
            *(short8*)&Bs[row * 72 + sc] = *(const short8*)(WLB + (size_t)row * DIM + kt + sc);
        }
        __syncthreads();
        #pragma unroll
        for (int kc = 0; kc < 2; ++kc) {
            const short8 af = *(const short8*)&AGs[(wq + lr) * 264 + kt + kc * 32 + lk * 8];
            #pragma unroll
            for (int ni = 0; ni < 8; ++ni) {
                const short8 bfr = *(const short8*)&Bs[(wn2 + ni * 16 + lr) * 72 + kc * 32 + lk * 8];
                accB[ni] = __builtin_amdgcn_mfma_f32_16x16x32_bf16(af, bfr, accB[ni], 0, 0, 0);
            }
        }
        __syncthreads();
    }
    float s1[4] = {0.f, 0.f, 0.f, 0.f}, s2[4] = {0.f, 0.f, 0.f, 0.f};
    #pragma unroll
    for (int ni = 0; ni < 8; ++ni) {
        const int col = wn2 + ni * 16 + lr;
        const float bv = bl[col];
        #pragma unroll
        for (int i = 0; i < 4; ++i) {
            const int rloc = wq + lk * 4 + i;
            const int t = (q0 + rloc) * 16 + m;
            const float z = accB[ni][i] + bv + bf2f(HB[((size_t)b * NTOK + t) * DIM + col]);
            accB[ni][i] = z;
            s1[i] += z; s2[i] += z * z;
        }
    }
    #pragma unroll
    for (int o = 1; o < 16; o <<= 1) {
        #pragma unroll
        for (int i = 0; i < 4; ++i) {
            s1[i] += __shfl_xor(s1[i], o);
            s2[i] += __shfl_xor(s2[i], o);
        }
    }
    if (lr == 0) {
        #pragma unroll
        for (int i = 0; i < 4; ++i) {
            const int rloc = wq + lk * 4 + i;
            s1buf[rloc][wv & 1] = s1[i];
            s2buf[rloc][wv & 1] = s2[i];
        }
    }
    __syncthreads();
    float mean[4], rstd[4];
    #pragma unroll
    for (int i = 0; i < 4; ++i) {
        const int rloc = wq + lk * 4 + i;
        const float t1 = s1buf[rloc][0] + s1buf[rloc][1];
        const float t2 = s2buf[rloc][0] + s2buf[rloc][1];
        const float mm = t1 * (1.f / DIM);
        mean[i] = mm;
        rstd[i] = rsqrtf(t2 * (1.f / DIM) - mm * mm + 1e-5f);
    }
    #pragma unroll
    for (int ni = 0; ni < 8; ++ni) {
        const int col = wn2 + ni * 16 + lr;
        const float gv = G[col], bv2 = Bt[col];
        #pragma unroll
        for (int i = 0; i < 4; ++i) {
            const int rloc = wq + lk * 4 + i;
            const int t = (q0 + rloc) * 16 + m;
            Y[((size_t)b * NTOK + t) * DIM + col] = (accB[ni][i] - mean[i]) * rstd[i] * gv + bv2;
        }
    }
}

extern "C" void kernel_launch(void* const* d_in, const int* in_sizes, int n_in,
                              void* d_out, int out_size, void* d_ws, size_t ws_size,
                              hipStream_t stream) {
    const float* x   = (const float*)d_in[0];
    const float* emb = (const float*)d_in[1];
    const float* Wa  = (const float*)d_in[2];
    const float* ba  = (const float*)d_in[3];
    const float* lng = (const float*)d_in[4];
    const float* lnb = (const float*)d_in[5];
    const float* Wc  = (const float*)d_in[6];
    const float* bc  = (const float*)d_in[7];
    const float* Wq  = (const float*)d_in[8];
    const float* bq  = (const float*)d_in[9];
    const float* Wk  = (const float*)d_in[10];
    const float* bk  = (const float*)d_in[11];
    const float* pw  = (const float*)d_in[12];
    const float* pb  = (const float*)d_in[13];
    const float* Wl  = (const float*)d_in[14];
    const float* bl  = (const float*)d_in[15];
    const float* ng  = (const float*)d_in[16];
    const float* nb  = (const float*)d_in[17];

    char* ws = (char*)d_ws;
    const size_t MB = 1024 * 1024;
    short* h_bf   = (short*)(ws + 0 * MB);    // 4 MB
    short* kvT    = (short*)(ws + 4 * MB);    // 4 MB
    short* act_bf = (short*)(ws + 8 * MB);    // 4 MB
    short* Wk_bf  = (short*)(ws + 12 * MB);   // 128 KB
    short* Wq_bf  = (short*)(ws + 12 * MB + 128 * 1024);
    short* Wl_bf  = (short*)(ws + 12 * MB + 256 * 1024);

    fused_dual<<<dim3(88, 4, 2), dim3(256), 0, stream>>>(x, Wa, ba, act_bf,
                                                         Wc, bc, h_bf, lng, lnb,
                                                         Wk, Wk_bf, Wq, Wq_bf, Wl, Wl_bf);
    kv_fused<<<dim3(32, 4, 2), dim3(256), 0, stream>>>(h_bf, Wk_bf, bk, kvT);
    attlin_fused<<<dim3(32, 8), dim3(256), 0, stream>>>(h_bf, Wq_bf, bq, kvT, emb, pw, pb,
                                                        act_bf, Wl_bf, bl, ng, nb, (float*)d_out);
}